// Round 6
// baseline (104.604 us; speedup 1.0000x reference)
//
#include <hip/hip_runtime.h>
#include <math.h>

// AFM forward, round 6: LUT-free arithmetic tile enumeration in pass 1.
// Pass-1 tiles = (row i, 16 consecutive j): all LDS addresses are affine in
// unrolled loop indices -> no data-dependent address chain, compiler can
// pipeline loads across tiles. i-row B-operand is a wave-broadcast read.
// Wave w handles rows i = w+8g (g=0..7); tiles/row = 4-(g>>1) (compile-time),
// 20 tiles/wave, perfectly balanced. Softmax / pass-2 MFMA / MLP tail
// identical to verified r5.

#define BB 512
#define FF 64
#define STR 68                // halves per row: 136B (34 dwords, gcd(34,32)=2)
#define NPAIRS 2080
#define THREADS 512
#define NEG_BIG -3.402823466e38f

typedef _Float16 half8 __attribute__((ext_vector_type(8)));
typedef _Float16 half4 __attribute__((ext_vector_type(4)));
typedef float f32x4 __attribute__((ext_vector_type(4)));

// 16B row-fragment load from an 8B-aligned row: two ds_read_b64.
__device__ __forceinline__ half8 ld8(const _Float16* p) {
    half8 v;
    *(half4*)&v       = *(const half4*)p;
    *((half4*)&v + 1) = *(const half4*)(p + 4);
    return v;
}

__global__ __launch_bounds__(THREADS, 4) void afm_r6_kernel(
    const float* __restrict__ x,     // [512,64]
    const float* __restrict__ Ww,    // [1,64]
    const float* __restrict__ bw,    // [1]
    const float* __restrict__ cross, // [64,64]
    const float* __restrict__ W1,    // [64,64]
    const float* __restrict__ b1,    // [64]
    const float* __restrict__ w2,    // [64]
    const float* __restrict__ Wd1,   // [32,64]
    const float* __restrict__ bd1,   // [32]
    const float* __restrict__ Wd2,   // [21,32]
    const float* __restrict__ bd2,   // [21]
    const float* __restrict__ Wd3,   // [16,21]
    const float* __restrict__ bd3,   // [16]
    const float* __restrict__ Wo,    // [1,16]
    const float* __restrict__ bo,    // [1]
    float* __restrict__ out)         // [512]
{
    __shared__ __align__(16) _Float16 ah_s [FF * STR];  // a[i][k] f16
    __shared__ __align__(16) _Float16 aht_s[FF * STR];  // a^T[k][i]
    __shared__ __align__(16) _Float16 M_s  [FF * STR];  // e-matrix (upper-tri)
    __shared__ float s_s[NPAIRS];
    __shared__ float x_sh[FF];
    __shared__ float part_s[4][FF];
    __shared__ float mlp_s[FF];
    __shared__ float red_s[16];

    const int tid  = threadIdx.x;
    const int lane = tid & 63;
    const int wave = tid >> 6;
    const int b    = blockIdx.x;
    const int m    = lane & 15;
    const int q    = lane >> 4;

    // ---- stage x ----
    if (tid < FF) x_sh[tid] = x[b * FF + tid];
    __syncthreads();

    // ---- ah/aht (f16), M zero ----
    for (int idx = tid; idx < FF * FF; idx += THREADS) {
        const int i = idx >> 6, k = idx & 63;
        const _Float16 v = (_Float16)(x_sh[i] * cross[idx]);
        ah_s[i * STR + k]  = v;
        aht_s[k * STR + i] = v;
    }
    for (int idx = tid; idx < (FF * STR) / 2; idx += THREADS)
        ((int*)M_s)[idx] = 0;

    // ---- A-fragments (W1->f16) from global; b1/w2 resident ----
    half8 afr[4][2];
    #pragma unroll
    for (int mt = 0; mt < 4; ++mt)
        #pragma unroll
        for (int kt = 0; kt < 2; ++kt) {
            const float* wr = W1 + (mt * 16 + m) * FF + kt * 32 + q * 8;
            half8 h;
            #pragma unroll
            for (int jj = 0; jj < 8; ++jj) h[jj] = (_Float16)wr[jj];
            afr[mt][kt] = h;
        }
    float b1r[16], w2r[16];
    #pragma unroll
    for (int mt = 0; mt < 4; ++mt)
        #pragma unroll
        for (int r = 0; r < 4; ++r) {
            b1r[mt * 4 + r] = b1[mt * 16 + q * 4 + r];
            w2r[mt * 4 + r] = w2[mt * 16 + q * 4 + r];
        }
    __syncthreads();

    // ---- pass 1: scores. Wave w: rows i = w+8g; tile t: j in [i+16t, i+16t+15] ----
    #pragma unroll
    for (int g = 0; g < 8; ++g) {
        const int i = wave + 8 * g;
        const int nt = 4 - (g >> 1);             // ceil((64-i)/16), compile-time
        const int basei = i * FF - (i * (i - 1)) / 2;
        const float xi = x_sh[i];
        // i-row fragment: same address across the wave -> LDS broadcast
        const half8 ai0 = ld8(&ah_s[i * STR + q * 8]);
        const half8 ai1 = ld8(&ah_s[i * STR + 32 + q * 8]);
        #pragma unroll
        for (int t = 0; t < nt; ++t) {
            const int j0 = i + 16 * t;
            const int jc = min(j0 + m, 63);      // clamped row (pad lanes read row 63)
            const half8 bf0 = ai0 * ld8(&ah_s[jc * STR + q * 8]);
            const half8 bf1 = ai1 * ld8(&ah_s[jc * STR + 32 + q * 8]);
            const float xjv = x_sh[jc];
            float sp = 0.f;
            #pragma unroll
            for (int mt = 0; mt < 4; ++mt) {
                f32x4 acc;
                #pragma unroll
                for (int r = 0; r < 4; ++r) acc[r] = b1r[mt * 4 + r];
                acc = __builtin_amdgcn_mfma_f32_16x16x32_f16(afr[mt][0], bf0, acc, 0, 0, 0);
                acc = __builtin_amdgcn_mfma_f32_16x16x32_f16(afr[mt][1], bf1, acc, 0, 0, 0);
                #pragma unroll
                for (int r = 0; r < 4; ++r)
                    sp = fmaf(w2r[mt * 4 + r], fmaxf(acc[r], 0.f), sp);
            }
            sp += __shfl_xor(sp, 16, 64);
            sp += __shfl_xor(sp, 32, 64);
            const bool valid = (xi != 0.f) && (xjv != 0.f);
            if (lane < 16 && (j0 + lane) < FF)
                s_s[basei + 16 * t + lane] = valid ? sp : NEG_BIG;
        }
    }
    __syncthreads();

    // ---- softmax max (0-seeded) ----
    float mx = 0.0f;
    for (int p = tid; p < NPAIRS; p += THREADS) mx = fmaxf(mx, s_s[p]);
    #pragma unroll
    for (int off = 32; off > 0; off >>= 1)
        mx = fmaxf(mx, __shfl_xor(mx, off, 64));
    if (lane == 0) red_s[wave] = mx;
    __syncthreads();
    float mval = red_s[0];
    #pragma unroll
    for (int w = 1; w < 8; ++w) mval = fmaxf(mval, red_s[w]);

    // ---- fused: e = exp(s-m), M[i][j] = e, sum e (arithmetic p-mapping) ----
    float sum = 0.f;
    for (int idx = tid; idx < FF * FF; idx += THREADS) {
        const int i = idx >> 6, j = idx & 63;
        if (j >= i) {
            const int p = i * FF - (i * (i - 1)) / 2 + (j - i);
            const float e = __expf(s_s[p] - mval);   // NEG_BIG -> 0
            sum += e;
            M_s[i * STR + j] = (_Float16)e;
        }
    }
    #pragma unroll
    for (int off = 32; off > 0; off >>= 1)
        sum += __shfl_xor(sum, off, 64);
    if (lane == 0) red_s[8 + wave] = sum;
    __syncthreads();
    float denom = __expf(-mval);
    #pragma unroll
    for (int w = 0; w < 8; ++w) denom += red_s[8 + w];

    // ---- pass 2 as MFMA: g = M @ ah; tmp[k] = sum_i ah[i][k]*g[i][k] ----
    {
        const int t0 = wave * 2;
        #pragma unroll
        for (int t = t0; t < t0 + 2; ++t) {
            const int i0 = (t >> 2) * 16, k0 = (t & 3) * 16;
            const half8 a0  = ld8(&M_s[(i0 + m) * STR + q * 8]);
            const half8 a1  = ld8(&M_s[(i0 + m) * STR + 32 + q * 8]);
            const half8 bb0 = ld8(&aht_s[(k0 + m) * STR + q * 8]);
            const half8 bb1 = ld8(&aht_s[(k0 + m) * STR + 32 + q * 8]);
            f32x4 gacc = {0.f, 0.f, 0.f, 0.f};
            gacc = __builtin_amdgcn_mfma_f32_16x16x32_f16(a0, bb0, gacc, 0, 0, 0);
            gacc = __builtin_amdgcn_mfma_f32_16x16x32_f16(a1, bb1, gacc, 0, 0, 0);
            const half4 ap = *(const half4*)&aht_s[(k0 + m) * STR + i0 + q * 4];
            float s4 = (float)ap[0] * gacc[0] + (float)ap[1] * gacc[1]
                     + (float)ap[2] * gacc[2] + (float)ap[3] * gacc[3];
            s4 += __shfl_xor(s4, 16, 64);
            s4 += __shfl_xor(s4, 32, 64);
            if (lane < 16) part_s[i0 >> 4][k0 + lane] = s4;
        }
    }
    __syncthreads();
    if (tid < FF)
        mlp_s[tid] = (part_s[0][tid] + part_s[1][tid] +
                      part_s[2][tid] + part_s[3][tid]) / denom;
    __syncthreads();

    // ---- deep MLP: 64 -> 32 -> 21 -> 16 -> 1 ----
    float hv = 0.f;
    if (tid < 32) {
        float a1v = bd1[tid];
        for (int k = 0; k < 64; ++k) a1v = fmaf(Wd1[tid * 64 + k], mlp_s[k], a1v);
        hv = fmaxf(a1v, 0.f);
    }
    __syncthreads();
    if (tid < 32) mlp_s[tid] = hv;
    __syncthreads();
    if (tid < 21) {
        float a2 = bd2[tid];
        for (int k = 0; k < 32; ++k) a2 = fmaf(Wd2[tid * 32 + k], mlp_s[k], a2);
        hv = fmaxf(a2, 0.f);
    }
    __syncthreads();
    if (tid < 21) mlp_s[tid] = hv;
    __syncthreads();
    if (tid < 16) {
        float a3 = bd3[tid];
        for (int k = 0; k < 21; ++k) a3 = fmaf(Wd3[tid * 21 + k], mlp_s[k], a3);
        hv = fmaxf(a3, 0.f);
    }
    __syncthreads();
    if (tid < 16) mlp_s[tid] = hv;
    __syncthreads();

    if (tid == 0) {
        float deep = bo[0];
        for (int k = 0; k < 16; ++k) deep = fmaf(Wo[k], mlp_s[k], deep);
        float lin = bw[0];
        for (int k = 0; k < 64; ++k) lin = fmaf(Ww[k], x_sh[k], lin);
        const float z = lin + deep;
        out[b] = 1.f / (1.f + __expf(-z));
    }
}

extern "C" void kernel_launch(void* const* d_in, const int* in_sizes, int n_in,
                              void* d_out, int out_size, void* d_ws, size_t ws_size,
                              hipStream_t stream) {
    const float* xp    = (const float*)d_in[0];
    const float* Ww    = (const float*)d_in[1];
    const float* bw    = (const float*)d_in[2];
    const float* cross = (const float*)d_in[3];
    const float* W1    = (const float*)d_in[4];
    const float* b1    = (const float*)d_in[5];
    const float* w2    = (const float*)d_in[6];
    const float* Wd1   = (const float*)d_in[7];
    const float* bd1   = (const float*)d_in[8];
    const float* Wd2   = (const float*)d_in[9];
    const float* bd2   = (const float*)d_in[10];
    const float* Wd3   = (const float*)d_in[11];
    const float* bd3   = (const float*)d_in[12];
    const float* Wo    = (const float*)d_in[13];
    const float* bo    = (const float*)d_in[14];
    float* outp = (float*)d_out;

    afm_r6_kernel<<<BB, THREADS, 0, stream>>>(xp, Ww, bw, cross, W1, b1, w2,
                                              Wd1, bd1, Wd2, bd2, Wd3, bd3,
                                              Wo, bo, outp);
}